// Round 7
// baseline (365.435 us; speedup 1.0000x reference)
//
#include <hip/hip_runtime.h>
#include <stdint.h>

constexpr int kHW = 16384;   // 128*128 pixels (grid shared across batch)
constexpr int kB  = 4;
constexpr int kM  = 256;     // tokens

typedef _Float16 half8 __attribute__((ext_vector_type(8)));  // 8 fp16 (4 VGPRs)
typedef __attribute__((ext_vector_type(4))) float f32x4;     // MFMA accum

// ---------------- helpers ----------------
__device__ __forceinline__ unsigned short f2h(float f) {
  _Float16 h = (_Float16)f;
  return __builtin_bit_cast(unsigned short, h);
}
__device__ __forceinline__ float h2f(unsigned short u) {
  return (float)__builtin_bit_cast(_Float16, u);
}
__device__ __forceinline__ float unpk(unsigned p, int hi) {
  return h2f((unsigned short)(p >> (hi * 16)));
}
// XOR-swizzled LDS addressing (8-short chunks, chunk^row&7): start-bank spread,
// 2-way max on A-frag ds_read_b128 (free per m136). Rows 256 / 128 shorts wide.
__device__ __forceinline__ int swz256(int row, int col) {
  int ch = col >> 3;
  ch = (ch & ~7) | ((ch ^ row) & 7);
  return row * 256 + ch * 8 + (col & 7);
}
__device__ __forceinline__ int swz128(int row, int col) {
  int ch = col >> 3;
  ch = (ch & 8) | ((ch ^ row) & 7);
  return row * 128 + ch * 8 + (col & 7);
}

// ---------------- kernel 0: weight prep (transpose + fp16) ----------------
__global__ __launch_bounds__(256) void wprep_kernel(
    const float* __restrict__ tooW, const float* __restrict__ modW0,
    const float* __restrict__ modW1, const float* __restrict__ hvW0,
    const float* __restrict__ qW, const float* __restrict__ bwW0,
    const float* __restrict__ bwW1, const float* __restrict__ toqW,
    unsigned short* __restrict__ tooWt, unsigned short* __restrict__ modW0t,
    unsigned short* __restrict__ modW1t, unsigned short* __restrict__ hvW0t,
    unsigned short* __restrict__ qWt, unsigned short* __restrict__ bw0t,
    unsigned short* __restrict__ bw1t, unsigned short* __restrict__ toqWt)
{
  int m = blockIdx.x, tid = threadIdx.x;
  const float* Ws[8] = {tooW, modW0, modW1, hvW0, qW, bwW0, bwW1, toqW};
  unsigned short* Wts[8] = {tooWt, modW0t, modW1t, hvW0t, qWt, bw0t, bw1t, toqWt};
  const int Ks[8] = {128, 256, 256, 256, 64, 64, 64, 256};
  const int Ns[8] = {256, 256, 256, 256, 256, 256, 256, 128};
  const float* W = Ws[m];
  unsigned short* Wt = Wts[m];
  int K = Ks[m], N = Ns[m];
  if (tid < N) {
    for (int kb = 0; kb < K / 8; kb++) {
      unsigned short sv[8];
#pragma unroll
      for (int i = 0; i < 8; i++)
        sv[i] = f2h(W[(kb * 8 + i) * N + tid]);   // coalesced across tid
      *(uint4*)&Wt[tid * K + kb * 8] = *(const uint4*)sv;
    }
  }
}

// ---------------- kernel 1: kv = tokens @ tokvW -> K natural + V transposed, fp16 ----------------
__global__ __launch_bounds__(256) void kv_kernel(
    const float* __restrict__ tokens, const float* __restrict__ tokvW,
    unsigned short* __restrict__ kn_ws, unsigned short* __restrict__ vt_ws)
{
  __shared__ __align__(16) float tok[256];
  int b = blockIdx.y, j = blockIdx.x, c = threadIdx.x;
  tok[c] = tokens[(b * kM + j) * 256 + c];
  __syncthreads();
  float acc = 0.f;
  for (int i4 = 0; i4 < 64; i4++) {
    float4 t4 = *(const float4*)&tok[i4 * 4];
    acc += t4.x * tokvW[(i4*4+0)*256 + c] + t4.y * tokvW[(i4*4+1)*256 + c]
         + t4.z * tokvW[(i4*4+2)*256 + c] + t4.w * tokvW[(i4*4+3)*256 + c];
  }
  unsigned short hv = f2h(acc);
  if (c < 128) {
    int h = c >> 6, dd = c & 63;
    kn_ws[((size_t)(b*2+h)*256 + j) * 64 + dd] = hv;
  } else {
    int c2 = c - 128;
    int h = c2 >> 6, dd = c2 & 63;
    vt_ws[((size_t)(b*2+h)*64 + dd) * 256 + j] = hv;
  }
}

// ---------------- kernel 2: MFMA per-pixel features (unchanged from R6) ----------------
constexpr int kFPitch = 72;
constexpr int kXPitch = 264;

__global__ __launch_bounds__(256, 2) void feat_kernel(
    const float* __restrict__ coords,
    const float* __restrict__ Bq, const float* __restrict__ Bl0, const float* __restrict__ Bl1,
    const float* __restrict__ qb, const float* __restrict__ bwb0, const float* __restrict__ bwb1,
    const unsigned short* __restrict__ qWt, const unsigned short* __restrict__ bw0t,
    const unsigned short* __restrict__ bw1t, const unsigned short* __restrict__ toqWt,
    float* __restrict__ t_ws, unsigned short* __restrict__ qc_ws,
    unsigned short* __restrict__ h0_hf, unsigned short* __restrict__ h1_hf)
{
  __shared__ __align__(16) unsigned short ff_s[3][32][kFPitch];
  __shared__ __align__(16) unsigned short xq_s[32][kXPitch];
  __shared__ float coords_s[64];

  int tid = threadIdx.x;
  int px0 = blockIdx.x * 32;
  int w = tid >> 6, ln = tid & 63;
  int c = ln & 15, q = ln >> 4;

  if (tid < 64) coords_s[tid] = coords[px0 * 2 + tid];
  __syncthreads();

#pragma unroll
  for (int r = 0; r < 24; r++) {
    int v = r * 256 + tid;
    int mat = v >> 11;
    int p = (v >> 6) & 31;
    int f = v & 63;
    int fr = f & 31;
    const float* Bm = (mat == 0) ? Bq : (mat == 1 ? Bl0 : Bl1);
    float x = coords_s[p * 2 + 0];
    float y = coords_s[p * 2 + 1];
    float proj = 6.283185307179586f * (x * Bm[fr*2+0] + y * Bm[fr*2+1]);
    float s, cc;
    __sincosf(proj, &s, &cc);
    ff_s[mat][p][f] = f2h((f < 32) ? cc : s);
  }
  if (tid < 32) {
    float x = coords_s[tid * 2 + 0];
    float y = coords_s[tid * 2 + 1];
    int row = min(max((int)(x * 16.0f), 0), 15);
    int col = min(max((int)(y * 16.0f), 0), 15);
    t_ws[px0 + tid] = (float)(row * 16 + col) * (1.0f / 256.0f);
  }
  __syncthreads();

  const f32x4 zero4 = {0.f, 0.f, 0.f, 0.f};

  for (int mat = 0; mat < 3; mat++) {
    const unsigned short* Wt = (mat == 0) ? qWt : (mat == 1 ? bw0t : bw1t);
    const float* bias = (mat == 0) ? qb : (mat == 1 ? bwb0 : bwb1);
    f32x4 acc[8];
#pragma unroll
    for (int i = 0; i < 8; i++) acc[i] = zero4;
#pragma unroll
    for (int ks = 0; ks < 2; ks++) {
      int koff = ks * 32 + q * 8;
      half8 bfr[4];
#pragma unroll
      for (int nt = 0; nt < 4; nt++)
        bfr[nt] = *(const half8*)(Wt + (size_t)(w*64 + nt*16 + c) * 64 + koff);
      half8 afr[2];
#pragma unroll
      for (int mt = 0; mt < 2; mt++)
        afr[mt] = *(const half8*)(&ff_s[mat][mt*16 + c][koff]);
#pragma unroll
      for (int mt = 0; mt < 2; mt++)
#pragma unroll
        for (int nt = 0; nt < 4; nt++)
          acc[mt*4+nt] = __builtin_amdgcn_mfma_f32_16x16x32_f16(afr[mt], bfr[nt], acc[mt*4+nt], 0, 0, 0);
    }
    float bv[4];
#pragma unroll
    for (int nt = 0; nt < 4; nt++) bv[nt] = bias[w*64 + nt*16 + c];
#pragma unroll
    for (int mt = 0; mt < 2; mt++)
#pragma unroll
      for (int nt = 0; nt < 4; nt++)
#pragma unroll
        for (int rg = 0; rg < 4; rg++) {
          int row = mt*16 + q*4 + rg, col = w*64 + nt*16 + c;
          unsigned short hv = f2h(fmaxf(acc[mt*4+nt][rg] + bv[nt], 0.f));
          if (mat == 0)      xq_s[row][col] = hv;
          else if (mat == 1) h0_hf[((size_t)(px0 + row)) * 256 + col] = hv;
          else               h1_hf[((size_t)(px0 + row)) * 256 + col] = hv;
        }
  }
  __syncthreads();

  {
    f32x4 acc2[4];
#pragma unroll
    for (int i = 0; i < 4; i++) acc2[i] = zero4;
#pragma unroll
    for (int kt = 0; kt < 8; kt++) {
      int koff = kt * 32 + q * 8;
      half8 bfr[2];
#pragma unroll
      for (int nt = 0; nt < 2; nt++)
        bfr[nt] = *(const half8*)(toqWt + (size_t)(w*32 + nt*16 + c) * 256 + koff);
      half8 afr[2];
#pragma unroll
      for (int mt = 0; mt < 2; mt++)
        afr[mt] = *(const half8*)(&xq_s[mt*16 + c][koff]);
#pragma unroll
      for (int mt = 0; mt < 2; mt++)
#pragma unroll
        for (int nt = 0; nt < 2; nt++)
          acc2[mt*2+nt] = __builtin_amdgcn_mfma_f32_16x16x32_f16(afr[mt], bfr[nt], acc2[mt*2+nt], 0, 0, 0);
    }
#pragma unroll
    for (int mt = 0; mt < 2; mt++)
#pragma unroll
      for (int nt = 0; nt < 2; nt++)
#pragma unroll
        for (int rg = 0; rg < 4; rg++) {
          int row = mt*16 + q*4 + rg, col = w*32 + nt*16 + c;
          qc_ws[((size_t)(px0 + row)) * 128 + col] = f2h(acc2[mt*2+nt][rg]);
        }
  }
}

// ---------------- kernel 3: MFMA cross attention (swizzled P_s) ----------------
__global__ __launch_bounds__(256, 2) void attn_kernel(
    const unsigned short* __restrict__ kn_ws,
    const unsigned short* __restrict__ vt_ws,
    const unsigned short* __restrict__ qc_ws,
    const float* __restrict__ t_ws,
    unsigned short* __restrict__ o_hf)
{
  __shared__ __align__(16) unsigned short P_s[32 * 256];  // swizzled
  __shared__ float t_s[32];
  __shared__ float red_max[32][4];
  __shared__ float red_sum[32][4];

  int b = blockIdx.y;
  int px0 = blockIdx.x * 32;
  int tid = threadIdx.x;
  int w = tid >> 6, ln = tid & 63;
  int c = ln & 15, q = ln >> 4;

  if (tid < 32) t_s[tid] = t_ws[px0 + tid];

  const f32x4 zero4 = {0.f, 0.f, 0.f, 0.f};

  for (int h = 0; h < 2; h++) {
    __syncthreads();

    f32x4 acc[8];
#pragma unroll
    for (int i = 0; i < 8; i++) acc[i] = zero4;
    const unsigned short* kbase = kn_ws + (size_t)(b*2+h) * 256 * 64;
#pragma unroll
    for (int ks = 0; ks < 2; ks++) {
      int koff = ks * 32 + q * 8;
      half8 a0 = *(const half8*)(qc_ws + (size_t)(px0 + c) * 128 + h*64 + koff);
      half8 a1 = *(const half8*)(qc_ws + (size_t)(px0 + 16 + c) * 128 + h*64 + koff);
#pragma unroll
      for (int nt = 0; nt < 4; nt++) {
        half8 bf = *(const half8*)(kbase + (size_t)(w*64 + nt*16 + c) * 64 + koff);
        acc[0*4+nt] = __builtin_amdgcn_mfma_f32_16x16x32_f16(a0, bf, acc[0*4+nt], 0, 0, 0);
        acc[1*4+nt] = __builtin_amdgcn_mfma_f32_16x16x32_f16(a1, bf, acc[1*4+nt], 0, 0, 0);
      }
    }

    float lm[2][4];
#pragma unroll
    for (int mt = 0; mt < 2; mt++)
#pragma unroll
      for (int rg = 0; rg < 4; rg++) {
        int row = mt*16 + q*4 + rg;
        float tv = t_s[row];
        float mx = -1e30f;
#pragma unroll
        for (int nt = 0; nt < 4; nt++) {
          int token = w*64 + nt*16 + c;
          float pos = ((float)token + 0.5f) * (1.0f / 256.0f);
          float db = tv - pos;
          float sb = acc[mt*4+nt][rg] * 0.125f - 10.0f * db * db;
          acc[mt*4+nt][rg] = sb;
          mx = fmaxf(mx, sb);
        }
        lm[mt][rg] = mx;
      }
#pragma unroll
    for (int s = 1; s < 16; s <<= 1)
#pragma unroll
      for (int mt = 0; mt < 2; mt++)
#pragma unroll
        for (int rg = 0; rg < 4; rg++)
          lm[mt][rg] = fmaxf(lm[mt][rg], __shfl_xor(lm[mt][rg], s, 64));
    if (c == 0) {
#pragma unroll
      for (int mt = 0; mt < 2; mt++)
#pragma unroll
        for (int rg = 0; rg < 4; rg++)
          red_max[mt*16 + q*4 + rg][w] = lm[mt][rg];
    }
    __syncthreads();

    float ps[2][4];
#pragma unroll
    for (int mt = 0; mt < 2; mt++)
#pragma unroll
      for (int rg = 0; rg < 4; rg++) {
        int row = mt*16 + q*4 + rg;
        float gm = fmaxf(fmaxf(red_max[row][0], red_max[row][1]),
                         fmaxf(red_max[row][2], red_max[row][3]));
        float sum = 0.f;
#pragma unroll
        for (int nt = 0; nt < 4; nt++) {
          float e = __expf(acc[mt*4+nt][rg] - gm);
          sum += e;
          P_s[swz256(row, w*64 + nt*16 + c)] = f2h(e);
        }
        ps[mt][rg] = sum;
      }
#pragma unroll
    for (int s = 1; s < 16; s <<= 1)
#pragma unroll
      for (int mt = 0; mt < 2; mt++)
#pragma unroll
        for (int rg = 0; rg < 4; rg++)
          ps[mt][rg] += __shfl_xor(ps[mt][rg], s, 64);
    if (c == 0) {
#pragma unroll
      for (int mt = 0; mt < 2; mt++)
#pragma unroll
        for (int rg = 0; rg < 4; rg++)
          red_sum[mt*16 + q*4 + rg][w] = ps[mt][rg];
    }
    __syncthreads();

    f32x4 oacc[2] = {zero4, zero4};
    const unsigned short* vbase = vt_ws + (size_t)(b*2+h) * 64 * 256;
#pragma unroll
    for (int kt = 0; kt < 8; kt++) {
      int koff = kt * 32 + q * 8;
      half8 bf = *(const half8*)(vbase + (size_t)(w*16 + c) * 256 + koff);
      half8 a0 = *(const half8*)(&P_s[swz256(c, koff)]);
      half8 a1 = *(const half8*)(&P_s[swz256(16 + c, koff)]);
      oacc[0] = __builtin_amdgcn_mfma_f32_16x16x32_f16(a0, bf, oacc[0], 0, 0, 0);
      oacc[1] = __builtin_amdgcn_mfma_f32_16x16x32_f16(a1, bf, oacc[1], 0, 0, 0);
    }
#pragma unroll
    for (int mt = 0; mt < 2; mt++)
#pragma unroll
      for (int rg = 0; rg < 4; rg++) {
        int row = mt*16 + q*4 + rg;
        float rinv = 1.0f / (red_sum[row][0] + red_sum[row][1] +
                             red_sum[row][2] + red_sum[row][3]);
        o_hf[((size_t)(b * kHW + px0 + row)) * 128 + h*64 + w*16 + c] =
            f2h(oacc[mt][rg] * rinv);
      }
  }
}

// ---------------- kernel 4: MFMA MLP chain, fp16, M=64, swizzled LDS, m0 in regs ----------------
// LDS: abuf 32 KB (mod->S, swizzled) + obuf 16.5 KB (o swz128; then h0/h1 @pitch 264)
//      + scratch 3 KB = ~52 KB -> 3 blocks/CU.
__global__ __launch_bounds__(256, 3) void mlp_kernel(
    const unsigned short* __restrict__ o_hf,
    const unsigned short* __restrict__ h0_hf, const unsigned short* __restrict__ h1_hf,
    const unsigned short* __restrict__ tooWt, const float* __restrict__ toob,
    const unsigned short* __restrict__ modW0t, const float* __restrict__ modb0,
    const unsigned short* __restrict__ modW1t, const float* __restrict__ modb1,
    const unsigned short* __restrict__ hvW0t, const float* __restrict__ hvb0,
    const float* __restrict__ outW0, const float* __restrict__ outb0,
    const float* __restrict__ outW1, const float* __restrict__ outb1,
    float* __restrict__ dout)
{
  __shared__ __align__(16) unsigned short abuf[64 * 256];  // mod, then S (swizzled)
  __shared__ __align__(16) unsigned short obuf[8448];      // o (64x128 swz); then h0/h1 (2 x 16x264)
  __shared__ __align__(16) float scratch[64 * 3 * 4];

  int tid = threadIdx.x;
  int px0 = blockIdx.x * 16;
  int w = tid >> 6, ln = tid & 63;
  int c = ln & 15, q = ln >> 4;

  const f32x4 zero4 = {0.f, 0.f, 0.f, 0.f};
  f32x4 acc[16];

  // ---- stage o (64 rows x 128, swizzled) ----
#pragma unroll
  for (int i = 0; i < 4; i++) {
    int idx = i * 256 + tid;              // 1024 x uint4 (8 fp16)
    int r = idx >> 4, ch = idx & 15;
    int b = r >> 4, px = r & 15;
    uint4 v = *(const uint4*)(o_hf + ((size_t)(b * kHW + px0 + px)) * 128 + ch * 8);
    *(uint4*)&obuf[swz128(r, ch * 8)] = v;
  }
  __syncthreads();   // (1) o staged

  // ---- P1: mod = o @ tooW + toob (K=128, A from obuf) ----
#pragma unroll
  for (int i = 0; i < 16; i++) acc[i] = zero4;
#pragma unroll
  for (int ks = 0; ks < 4; ks++) {
    int koff = ks * 32 + q * 8;
    half8 bfr[4];
#pragma unroll
    for (int nt = 0; nt < 4; nt++)
      bfr[nt] = *(const half8*)(tooWt + (size_t)(w*64 + nt*16 + c) * 128 + koff);
    half8 afr[4];
#pragma unroll
    for (int mt = 0; mt < 4; mt++)
      afr[mt] = *(const half8*)&obuf[swz128(mt*16 + c, koff)];
#pragma unroll
    for (int mt = 0; mt < 4; mt++)
#pragma unroll
      for (int nt = 0; nt < 4; nt++)
        acc[mt*4+nt] = __builtin_amdgcn_mfma_f32_16x16x32_f16(afr[mt], bfr[nt], acc[mt*4+nt], 0, 0, 0);
  }
  __syncthreads();   // (2) all obuf (o) reads done

  // ---- write mod -> abuf; stage h0/h1 -> obuf region (pitch 264) ----
  {
    float bias[4];
#pragma unroll
    for (int nt = 0; nt < 4; nt++) bias[nt] = toob[w * 64 + nt * 16 + c];
#pragma unroll
    for (int mt = 0; mt < 4; mt++)
#pragma unroll
      for (int nt = 0; nt < 4; nt++)
#pragma unroll
        for (int rg = 0; rg < 4; rg++) {
          int row = mt * 16 + q * 4 + rg, col = w * 64 + nt * 16 + c;
          abuf[swz256(row, col)] = f2h(acc[mt * 4 + nt][rg] + bias[nt]);
        }
  }
#pragma unroll
  for (int i = 0; i < 2; i++) {
    int idx = i * 256 + tid;              // 512 x uint4 each
    int p = idx >> 5, c8 = (idx & 31) * 8;
    *(uint4*)&obuf[p * 264 + c8] =
        *(const uint4*)(h0_hf + ((size_t)(px0 + p)) * 256 + c8);
    *(uint4*)&obuf[4224 + p * 264 + c8] =
        *(const uint4*)(h1_hf + ((size_t)(px0 + p)) * 256 + c8);
  }
  __syncthreads();   // (3) mod + h0 + h1 ready

  // ---- P2: m0 = relu(h0 + mod @ modW0 + b) -> packed fp16 regs ----
#pragma unroll
  for (int i = 0; i < 16; i++) acc[i] = zero4;
#pragma unroll
  for (int ks = 0; ks < 8; ks++) {
    int koff = ks * 32 + q * 8;
    half8 bfr[4];
#pragma unroll
    for (int nt = 0; nt < 4; nt++)
      bfr[nt] = *(const half8*)(modW0t + (size_t)(w*64 + nt*16 + c) * 256 + koff);
    half8 afr[4];
#pragma unroll
    for (int mt = 0; mt < 4; mt++)
      afr[mt] = *(const half8*)&abuf[swz256(mt*16 + c, koff)];
#pragma unroll
    for (int mt = 0; mt < 4; mt++)
#pragma unroll
      for (int nt = 0; nt < 4; nt++)
        acc[mt*4+nt] = __builtin_amdgcn_mfma_f32_16x16x32_f16(afr[mt], bfr[nt], acc[mt*4+nt], 0, 0, 0);
  }
  unsigned m0p[16][2];   // m0 packed 2xfp16 per (mt*4+nt), rg pairs
  {
    float bias[4];
#pragma unroll
    for (int nt = 0; nt < 4; nt++) bias[nt] = modb0[w * 64 + nt * 16 + c];
#pragma unroll
    for (int mt = 0; mt < 4; mt++)
#pragma unroll
      for (int nt = 0; nt < 4; nt++) {
        int col = w * 64 + nt * 16 + c;
        unsigned short hp[4];
#pragma unroll
        for (int rg = 0; rg < 4; rg++) {
          float hv = h2f(obuf[(q * 4 + rg) * 264 + col]);
          hp[rg] = f2h(fmaxf(acc[mt * 4 + nt][rg] + bias[nt] + hv, 0.f));
        }
        m0p[mt * 4 + nt][0] = (unsigned)hp[0] | ((unsigned)hp[1] << 16);
        m0p[mt * 4 + nt][1] = (unsigned)hp[2] | ((unsigned)hp[3] << 16);
      }
  }
  // no barrier: abuf (mod) unchanged, P3 reads it again

  // ---- P3: m1 = relu(h1 + mod @ modW1 + b); S = m0 + m1 -> abuf ----
#pragma unroll
  for (int i = 0; i < 16; i++) acc[i] = zero4;
#pragma unroll
  for (int ks = 0; ks < 8; ks++) {
    int koff = ks * 32 + q * 8;
    half8 bfr[4];
#pragma unroll
    for (int nt = 0; nt < 4; nt++)
      bfr[nt] = *(const half8*)(modW1t + (size_t)(w*64 + nt*16 + c) * 256 + koff);
    half8 afr[4];
#pragma unroll
    for (int mt = 0; mt < 4; mt++)
      afr[mt] = *(const half8*)&abuf[swz256(mt*16 + c, koff)];
#pragma unroll
    for (int mt = 0; mt < 4; mt++)
#pragma unroll
      for (int nt = 0; nt < 4; nt++)
        acc[mt*4+nt] = __builtin_amdgcn_mfma_f32_16x16x32_f16(afr[mt], bfr[nt], acc[mt*4+nt], 0, 0, 0);
  }
  __syncthreads();   // (4) all mod reads done
  {
    float bias[4];
#pragma unroll
    for (int nt = 0; nt < 4; nt++) bias[nt] = modb1[w * 64 + nt * 16 + c];
#pragma unroll
    for (int mt = 0; mt < 4; mt++)
#pragma unroll
      for (int nt = 0; nt < 4; nt++) {
        int col = w * 64 + nt * 16 + c;
#pragma unroll
        for (int rg = 0; rg < 4; rg++) {
          int row = mt * 16 + q * 4 + rg;
          float hv = h2f(obuf[4224 + (q * 4 + rg) * 264 + col]);
          float m0v = unpk(m0p[mt * 4 + nt][rg >> 1], rg & 1);
          float v = m0v + fmaxf(acc[mt * 4 + nt][rg] + bias[nt] + hv, 0.f);
          abuf[swz256(row, col)] = f2h(v);
        }
      }
  }
  __syncthreads();   // (5) S ready

  // ---- P4: hv1 = relu(S @ hvW0 + b); P5 fused out epilogue ----
#pragma unroll
  for (int i = 0; i < 16; i++) acc[i] = zero4;
#pragma unroll
  for (int ks = 0; ks < 8; ks++) {
    int koff = ks * 32 + q * 8;
    half8 bfr[4];
#pragma unroll
    for (int nt = 0; nt < 4; nt++)
      bfr[nt] = *(const half8*)(hvW0t + (size_t)(w*64 + nt*16 + c) * 256 + koff);
    half8 afr[4];
#pragma unroll
    for (int mt = 0; mt < 4; mt++)
      afr[mt] = *(const half8*)&abuf[swz256(mt*16 + c, koff)];
#pragma unroll
    for (int mt = 0; mt < 4; mt++)
#pragma unroll
      for (int nt = 0; nt < 4; nt++)
        acc[mt*4+nt] = __builtin_amdgcn_mfma_f32_16x16x32_f16(afr[mt], bfr[nt], acc[mt*4+nt], 0, 0, 0);
  }
  {
    float bias[4], w0v[4][3], w1v[4][3];
#pragma unroll
    for (int nt = 0; nt < 4; nt++) {
      int col = w * 64 + nt * 16 + c;
      bias[nt] = hvb0[col];
#pragma unroll
      for (int k = 0; k < 3; k++) {
        w0v[nt][k] = outW0[col * 3 + k];
        w1v[nt][k] = outW1[col * 3 + k];
      }
    }
#pragma unroll
    for (int mt = 0; mt < 4; mt++) {
      float pk[4][3];
#pragma unroll
      for (int rg = 0; rg < 4; rg++)
#pragma unroll
        for (int k = 0; k < 3; k++) pk[rg][k] = 0.f;
#pragma unroll
      for (int nt = 0; nt < 4; nt++) {
#pragma unroll
        for (int rg = 0; rg < 4; rg++) {
          float hv1 = fmaxf(acc[mt * 4 + nt][rg] + bias[nt], 0.f);
          float m0v = unpk(m0p[mt * 4 + nt][rg >> 1], rg & 1);
#pragma unroll
          for (int k = 0; k < 3; k++)
            pk[rg][k] += m0v * w0v[nt][k] + hv1 * w1v[nt][k];
        }
      }
#pragma unroll
      for (int s = 1; s < 16; s <<= 1)
#pragma unroll
        for (int rg = 0; rg < 4; rg++)
#pragma unroll
          for (int k = 0; k < 3; k++)
            pk[rg][k] += __shfl_xor(pk[rg][k], s, 64);
      if (c == 0) {
#pragma unroll
        for (int rg = 0; rg < 4; rg++) {
          int row = mt * 16 + q * 4 + rg;
#pragma unroll
          for (int k = 0; k < 3; k++)
            scratch[row * 12 + k * 4 + w] = pk[rg][k];
        }
      }
    }
  }
  __syncthreads();   // (6) scratch ready

  if (tid < 192) {
    int row = tid / 3, k = tid % 3;
    int b = row >> 4, px = px0 + (row & 15);
    float s = outb0[k] + outb1[k];
#pragma unroll
    for (int ww = 0; ww < 4; ww++) s += scratch[row * 12 + k * 4 + ww];
    dout[((size_t)b * kHW + px) * 3 + k] = s;
  }
}

// ---------------- launch ----------------
extern "C" void kernel_launch(void* const* d_in, const int* in_sizes, int n_in,
                              void* d_out, int out_size, void* d_ws, size_t ws_size,
                              hipStream_t stream) {
  const float* coords = (const float*)d_in[0];
  const float* tokens = (const float*)d_in[1];
  const float* Bq     = (const float*)d_in[2];
  const float* Bl0    = (const float*)d_in[3];
  const float* Bl1    = (const float*)d_in[4];
  const float* qW     = (const float*)d_in[5];
  const float* qb     = (const float*)d_in[6];
  const float* toqW   = (const float*)d_in[7];
  const float* tokvW  = (const float*)d_in[8];
  const float* tooW   = (const float*)d_in[9];
  const float* toob   = (const float*)d_in[10];
  const float* bwW0   = (const float*)d_in[11];
  const float* bwb0   = (const float*)d_in[12];
  const float* bwW1   = (const float*)d_in[13];
  const float* bwb1   = (const float*)d_in[14];
  const float* modW0  = (const float*)d_in[15];
  const float* modb0  = (const float*)d_in[16];
  const float* modW1  = (const float*)d_in[17];
  const float* modb1  = (const float*)d_in[18];
  const float* hvW0   = (const float*)d_in[19];
  const float* hvb0   = (const float*)d_in[20];
  const float* outW0  = (const float*)d_in[21];
  const float* outb0  = (const float*)d_in[22];
  const float* outW1  = (const float*)d_in[23];
  const float* outb1  = (const float*)d_in[24];

  char* ws = (char*)d_ws;
  float*          t_ws   = (float*)(ws + 0);                  //   64 KB
  unsigned short* qc_ws  = (unsigned short*)(ws + 65536);     //    4 MB
  unsigned short* h0_hf  = (unsigned short*)(ws + 4259840);   //    8 MB
  unsigned short* h1_hf  = (unsigned short*)(ws + 12648448);  //    8 MB
  unsigned short* o_hf   = (unsigned short*)(ws + 21037056);  //   16 MB
  unsigned short* kn_ws  = (unsigned short*)(ws + 37814272);  //  256 KB
  unsigned short* vt_ws  = (unsigned short*)(ws + 38076416);  //  256 KB
  unsigned short* tooWt  = (unsigned short*)(ws + 38338560);  //   64 KB
  unsigned short* modW0t = (unsigned short*)(ws + 38404096);  //  128 KB
  unsigned short* modW1t = (unsigned short*)(ws + 38535168);  //  128 KB
  unsigned short* hvW0t  = (unsigned short*)(ws + 38666240);  //  128 KB
  unsigned short* qWt    = (unsigned short*)(ws + 38797312);  //   32 KB
  unsigned short* bw0t   = (unsigned short*)(ws + 38830080);  //   32 KB
  unsigned short* bw1t   = (unsigned short*)(ws + 38862848);  //   32 KB
  unsigned short* toqWt  = (unsigned short*)(ws + 38895616);  //   64 KB

  wprep_kernel<<<dim3(8), 256, 0, stream>>>(
      tooW, modW0, modW1, hvW0, qW, bwW0, bwW1, toqW,
      tooWt, modW0t, modW1t, hvW0t, qWt, bw0t, bw1t, toqWt);
  feat_kernel<<<dim3(kHW / 32), 256, 0, stream>>>(
      coords, Bq, Bl0, Bl1, qb, bwb0, bwb1,
      qWt, bw0t, bw1t, toqWt,
      t_ws, qc_ws, h0_hf, h1_hf);
  kv_kernel<<<dim3(kM, kB), 256, 0, stream>>>(tokens, tokvW, kn_ws, vt_ws);
  attn_kernel<<<dim3(kHW / 32, kB), 256, 0, stream>>>(kn_ws, vt_ws, qc_ws, t_ws, o_hf);
  mlp_kernel<<<dim3(kHW / 16), 256, 0, stream>>>(
      o_hf, h0_hf, h1_hf, tooWt, toob, modW0t, modb0, modW1t, modb1,
      hvW0t, hvb0, outW0, outb0, outW1, outb1, (float*)d_out);
}

// Round 8
// 282.821 us; speedup vs baseline: 1.2921x; 1.2921x over previous
//
#include <hip/hip_runtime.h>
#include <stdint.h>

constexpr int kHW = 16384;   // 128*128 pixels (grid shared across batch)
constexpr int kB  = 4;
constexpr int kM  = 256;     // tokens

typedef _Float16 half8 __attribute__((ext_vector_type(8)));  // 8 fp16 (4 VGPRs)
typedef __attribute__((ext_vector_type(4))) float f32x4;     // MFMA accum

// ---------------- helpers ----------------
__device__ __forceinline__ unsigned short f2h(float f) {
  _Float16 h = (_Float16)f;
  return __builtin_bit_cast(unsigned short, h);
}
__device__ __forceinline__ float h2f(unsigned short u) {
  return (float)__builtin_bit_cast(_Float16, u);
}
// XOR swizzle for 256-short-wide rows (8-short chunks): conflict-free b128 A-reads.
__device__ __forceinline__ int swz256(int row, int col) {
  int ch = col >> 3;
  ch = (ch & ~7) | ((ch ^ row) & 7);
  return row * 256 + ch * 8 + (col & 7);
}

// ---------------- kernel 0: weight prep (transpose + fp16) ----------------
__global__ __launch_bounds__(256) void wprep_kernel(
    const float* __restrict__ tooW, const float* __restrict__ modW0,
    const float* __restrict__ modW1, const float* __restrict__ hvW0,
    const float* __restrict__ qW, const float* __restrict__ bwW0,
    const float* __restrict__ bwW1, const float* __restrict__ toqW,
    unsigned short* __restrict__ tooWt, unsigned short* __restrict__ modW0t,
    unsigned short* __restrict__ modW1t, unsigned short* __restrict__ hvW0t,
    unsigned short* __restrict__ qWt, unsigned short* __restrict__ bw0t,
    unsigned short* __restrict__ bw1t, unsigned short* __restrict__ toqWt)
{
  int m = blockIdx.x, tid = threadIdx.x;
  const float* Ws[8] = {tooW, modW0, modW1, hvW0, qW, bwW0, bwW1, toqW};
  unsigned short* Wts[8] = {tooWt, modW0t, modW1t, hvW0t, qWt, bw0t, bw1t, toqWt};
  const int Ks[8] = {128, 256, 256, 256, 64, 64, 64, 256};
  const int Ns[8] = {256, 256, 256, 256, 256, 256, 256, 128};
  const float* W = Ws[m];
  unsigned short* Wt = Wts[m];
  int K = Ks[m], N = Ns[m];
  if (tid < N) {
    for (int kb = 0; kb < K / 8; kb++) {
      unsigned short sv[8];
#pragma unroll
      for (int i = 0; i < 8; i++)
        sv[i] = f2h(W[(kb * 8 + i) * N + tid]);   // coalesced across tid
      *(uint4*)&Wt[tid * K + kb * 8] = *(const uint4*)sv;
    }
  }
}

// ---------------- kernel 1: kv = tokens @ tokvW -> K natural + V transposed, fp16 ----------------
__global__ __launch_bounds__(256) void kv_kernel(
    const float* __restrict__ tokens, const float* __restrict__ tokvW,
    unsigned short* __restrict__ kn_ws, unsigned short* __restrict__ vt_ws)
{
  __shared__ __align__(16) float tok[256];
  int b = blockIdx.y, j = blockIdx.x, c = threadIdx.x;
  tok[c] = tokens[(b * kM + j) * 256 + c];
  __syncthreads();
  float acc = 0.f;
  for (int i4 = 0; i4 < 64; i4++) {
    float4 t4 = *(const float4*)&tok[i4 * 4];
    acc += t4.x * tokvW[(i4*4+0)*256 + c] + t4.y * tokvW[(i4*4+1)*256 + c]
         + t4.z * tokvW[(i4*4+2)*256 + c] + t4.w * tokvW[(i4*4+3)*256 + c];
  }
  unsigned short hv = f2h(acc);
  if (c < 128) {
    int h = c >> 6, dd = c & 63;
    kn_ws[((size_t)(b*2+h)*256 + j) * 64 + dd] = hv;
  } else {
    int c2 = c - 128;
    int h = c2 >> 6, dd = c2 & 63;
    vt_ws[((size_t)(b*2+h)*64 + dd) * 256 + j] = hv;
  }
}

// ---------------- kernel 2: MFMA per-pixel features (R6-proven, t_ws removed) ----------------
constexpr int kFPitch = 72;
constexpr int kXPitch = 264;

__global__ __launch_bounds__(256, 2) void feat_kernel(
    const float* __restrict__ coords,
    const float* __restrict__ Bq, const float* __restrict__ Bl0, const float* __restrict__ Bl1,
    const float* __restrict__ qb, const float* __restrict__ bwb0, const float* __restrict__ bwb1,
    const unsigned short* __restrict__ qWt, const unsigned short* __restrict__ bw0t,
    const unsigned short* __restrict__ bw1t, const unsigned short* __restrict__ toqWt,
    unsigned short* __restrict__ qc_ws,
    unsigned short* __restrict__ h0_hf, unsigned short* __restrict__ h1_hf)
{
  __shared__ __align__(16) unsigned short ff_s[3][32][kFPitch];
  __shared__ __align__(16) unsigned short xq_s[32][kXPitch];
  __shared__ float coords_s[64];

  int tid = threadIdx.x;
  int px0 = blockIdx.x * 32;
  int w = tid >> 6, ln = tid & 63;
  int c = ln & 15, q = ln >> 4;

  if (tid < 64) coords_s[tid] = coords[px0 * 2 + tid];
  __syncthreads();

#pragma unroll
  for (int r = 0; r < 24; r++) {
    int v = r * 256 + tid;
    int mat = v >> 11;
    int p = (v >> 6) & 31;
    int f = v & 63;
    int fr = f & 31;
    const float* Bm = (mat == 0) ? Bq : (mat == 1 ? Bl0 : Bl1);
    float x = coords_s[p * 2 + 0];
    float y = coords_s[p * 2 + 1];
    float proj = 6.283185307179586f * (x * Bm[fr*2+0] + y * Bm[fr*2+1]);
    float s, cc;
    __sincosf(proj, &s, &cc);
    ff_s[mat][p][f] = f2h((f < 32) ? cc : s);
  }
  __syncthreads();

  const f32x4 zero4 = {0.f, 0.f, 0.f, 0.f};

  for (int mat = 0; mat < 3; mat++) {
    const unsigned short* Wt = (mat == 0) ? qWt : (mat == 1 ? bw0t : bw1t);
    const float* bias = (mat == 0) ? qb : (mat == 1 ? bwb0 : bwb1);
    f32x4 acc[8];
#pragma unroll
    for (int i = 0; i < 8; i++) acc[i] = zero4;
#pragma unroll
    for (int ks = 0; ks < 2; ks++) {
      int koff = ks * 32 + q * 8;
      half8 bfr[4];
#pragma unroll
      for (int nt = 0; nt < 4; nt++)
        bfr[nt] = *(const half8*)(Wt + (size_t)(w*64 + nt*16 + c) * 64 + koff);
      half8 afr[2];
#pragma unroll
      for (int mt = 0; mt < 2; mt++)
        afr[mt] = *(const half8*)(&ff_s[mat][mt*16 + c][koff]);
#pragma unroll
      for (int mt = 0; mt < 2; mt++)
#pragma unroll
        for (int nt = 0; nt < 4; nt++)
          acc[mt*4+nt] = __builtin_amdgcn_mfma_f32_16x16x32_f16(afr[mt], bfr[nt], acc[mt*4+nt], 0, 0, 0);
    }
    float bv[4];
#pragma unroll
    for (int nt = 0; nt < 4; nt++) bv[nt] = bias[w*64 + nt*16 + c];
#pragma unroll
    for (int mt = 0; mt < 2; mt++)
#pragma unroll
      for (int nt = 0; nt < 4; nt++)
#pragma unroll
        for (int rg = 0; rg < 4; rg++) {
          int row = mt*16 + q*4 + rg, col = w*64 + nt*16 + c;
          unsigned short hv = f2h(fmaxf(acc[mt*4+nt][rg] + bv[nt], 0.f));
          if (mat == 0)      xq_s[row][col] = hv;
          else if (mat == 1) h0_hf[((size_t)(px0 + row)) * 256 + col] = hv;
          else               h1_hf[((size_t)(px0 + row)) * 256 + col] = hv;
        }
  }
  __syncthreads();

  {
    f32x4 acc2[4];
#pragma unroll
    for (int i = 0; i < 4; i++) acc2[i] = zero4;
#pragma unroll
    for (int kt = 0; kt < 8; kt++) {
      int koff = kt * 32 + q * 8;
      half8 bfr[2];
#pragma unroll
      for (int nt = 0; nt < 2; nt++)
        bfr[nt] = *(const half8*)(toqWt + (size_t)(w*32 + nt*16 + c) * 256 + koff);
      half8 afr[2];
#pragma unroll
      for (int mt = 0; mt < 2; mt++)
        afr[mt] = *(const half8*)(&xq_s[mt*16 + c][koff]);
#pragma unroll
      for (int mt = 0; mt < 2; mt++)
#pragma unroll
        for (int nt = 0; nt < 2; nt++)
          acc2[mt*2+nt] = __builtin_amdgcn_mfma_f32_16x16x32_f16(afr[mt], bfr[nt], acc2[mt*2+nt], 0, 0, 0);
    }
#pragma unroll
    for (int mt = 0; mt < 2; mt++)
#pragma unroll
      for (int nt = 0; nt < 2; nt++)
#pragma unroll
        for (int rg = 0; rg < 4; rg++) {
          int row = mt*16 + q*4 + rg, col = w*32 + nt*16 + c;
          qc_ws[((size_t)(px0 + row)) * 128 + col] = f2h(acc2[mt*2+nt][rg]);
        }
  }
}

// ---------------- kernel 3: MFMA cross attention, M-split (wave-private softmax) ----------------
// Block = 64 px x 1 batch, 4 waves; wave w owns rows [w*16, w*16+16) -- full 256-token
// rows, so softmax reductions are intra-wave shfl only. P_s bands wave-private (swizzled).
// One safety barrier per head (P_s write -> b128 read ordering).
__global__ __launch_bounds__(256, 2) void attn_kernel(
    const unsigned short* __restrict__ kn_ws,
    const unsigned short* __restrict__ vt_ws,
    const unsigned short* __restrict__ qc_ws,
    const float* __restrict__ coords,
    unsigned short* __restrict__ o_hf)
{
  __shared__ __align__(16) unsigned short P_s[64 * 256];  // swizzled, wave band = 16 rows

  int b = blockIdx.y;
  int px0 = blockIdx.x * 64;
  int tid = threadIdx.x;
  int w = tid >> 6, ln = tid & 63;
  int c = ln & 15, q = ln >> 4;

  // t for the 4 rows this lane owns (row = w*16 + q*4 + rg)
  float tv[4];
#pragma unroll
  for (int rg = 0; rg < 4; rg++) {
    int px = px0 + w*16 + q*4 + rg;
    float x = coords[px*2 + 0], y = coords[px*2 + 1];
    int r = min(max((int)(x * 16.0f), 0), 15);
    int cl = min(max((int)(y * 16.0f), 0), 15);
    tv[rg] = (float)(r * 16 + cl) * (1.0f / 256.0f);
  }

  const f32x4 zero4 = {0.f, 0.f, 0.f, 0.f};

  for (int h = 0; h < 2; h++) {
    // ---- QK^T: M=16 (wave rows), N=256 (16 nt), K=64 ----
    f32x4 acc[16];
#pragma unroll
    for (int i = 0; i < 16; i++) acc[i] = zero4;
    const unsigned short* kbase = kn_ws + (size_t)(b*2+h) * 256 * 64;
    const unsigned short* qrow = qc_ws + (size_t)(px0 + w*16 + c) * 128 + h*64;
    half8 a0 = *(const half8*)(qrow + q*8);
    half8 a1 = *(const half8*)(qrow + 32 + q*8);
#pragma unroll
    for (int nt = 0; nt < 16; nt++) {
      const unsigned short* kr = kbase + (size_t)(nt*16 + c) * 64 + q*8;
      half8 b0 = *(const half8*)(kr);
      half8 b1 = *(const half8*)(kr + 32);
      acc[nt] = __builtin_amdgcn_mfma_f32_16x16x32_f16(a0, b0, acc[nt], 0, 0, 0);
      acc[nt] = __builtin_amdgcn_mfma_f32_16x16x32_f16(a1, b1, acc[nt], 0, 0, 0);
    }

    // ---- bias + scale in place; row max over nt then shfl over c-lanes ----
    float lm[4];
#pragma unroll
    for (int rg = 0; rg < 4; rg++) {
      float mx = -1e30f;
#pragma unroll
      for (int nt = 0; nt < 16; nt++) {
        float pos = ((float)(nt*16 + c) + 0.5f) * (1.0f / 256.0f);
        float db = tv[rg] - pos;
        float sb = acc[nt][rg] * 0.125f - 10.0f * db * db;
        acc[nt][rg] = sb;
        mx = fmaxf(mx, sb);
      }
      lm[rg] = mx;
    }
#pragma unroll
    for (int s = 1; s < 16; s <<= 1)
#pragma unroll
      for (int rg = 0; rg < 4; rg++)
        lm[rg] = fmaxf(lm[rg], __shfl_xor(lm[rg], s, 64));

    // ---- exp, P_s write (wave band), row sum ----
    float linv[4];
#pragma unroll
    for (int rg = 0; rg < 4; rg++) {
      float sum = 0.f;
      int row = w*16 + q*4 + rg;
#pragma unroll
      for (int nt = 0; nt < 16; nt++) {
        float e = __expf(acc[nt][rg] - lm[rg]);
        sum += e;
        P_s[swz256(row, nt*16 + c)] = f2h(e);
      }
      linv[rg] = sum;
    }
#pragma unroll
    for (int s = 1; s < 16; s <<= 1)
#pragma unroll
      for (int rg = 0; rg < 4; rg++)
        linv[rg] += __shfl_xor(linv[rg], s, 64);
#pragma unroll
    for (int rg = 0; rg < 4; rg++) linv[rg] = 1.0f / linv[rg];

    __syncthreads();   // order P_s writes before b128 reads (conservative)

    // ---- PV: M=16, N=64 dh (4 nt), K=256 ----
    f32x4 oacc[4];
#pragma unroll
    for (int i = 0; i < 4; i++) oacc[i] = zero4;
    const unsigned short* vbase = vt_ws + (size_t)(b*2+h) * 64 * 256;
#pragma unroll
    for (int kt = 0; kt < 8; kt++) {
      int koff = kt * 32 + q * 8;
      half8 af = *(const half8*)&P_s[swz256(w*16 + c, koff)];
#pragma unroll
      for (int nt = 0; nt < 4; nt++) {
        half8 bf = *(const half8*)(vbase + (size_t)(nt*16 + c) * 256 + koff);
        oacc[nt] = __builtin_amdgcn_mfma_f32_16x16x32_f16(af, bf, oacc[nt], 0, 0, 0);
      }
    }
#pragma unroll
    for (int nt = 0; nt < 4; nt++)
#pragma unroll
      for (int rg = 0; rg < 4; rg++) {
        int row = w*16 + q*4 + rg;
        o_hf[((size_t)(b * kHW + px0 + row)) * 128 + h*64 + nt*16 + c] =
            f2h(oacc[nt][rg] * linv[rg]);
      }
    __syncthreads();   // P_s band reuse for next head (conservative)
  }
}

// ---------------- kernel 4: MFMA MLP chain (exact R6 version, 76 us known-good) ----------------
constexpr int kPitch = 264;   // fp16 LDS pitch

template <int KD>
__device__ __forceinline__ void gemm4(
    const unsigned short* abuf, const unsigned short* wt,
    f32x4* acc /*[4*4]*/, int c, int q)
{
#pragma unroll
  for (int ks = 0; ks < KD / 32; ks++) {
    int koff = ks * 32 + q * 8;
    half8 bfr[4];
#pragma unroll
    for (int nt = 0; nt < 4; nt++)
      bfr[nt] = *(const half8*)(wt + (nt * 16 + c) * KD + koff);
    half8 afr[4];
#pragma unroll
    for (int mt = 0; mt < 4; mt++)
      afr[mt] = *(const half8*)(abuf + (mt * 16 + c) * kPitch + koff);
#pragma unroll
    for (int mt = 0; mt < 4; mt++)
#pragma unroll
      for (int nt = 0; nt < 4; nt++)
        acc[mt * 4 + nt] = __builtin_amdgcn_mfma_f32_16x16x32_f16(afr[mt], bfr[nt], acc[mt * 4 + nt], 0, 0, 0);
  }
}

__global__ __launch_bounds__(256, 2) void mlp_kernel(
    const unsigned short* __restrict__ o_hf,
    const unsigned short* __restrict__ h0_hf, const unsigned short* __restrict__ h1_hf,
    const unsigned short* __restrict__ tooWt, const float* __restrict__ toob,
    const unsigned short* __restrict__ modW0t, const float* __restrict__ modb0,
    const unsigned short* __restrict__ modW1t, const float* __restrict__ modb1,
    const unsigned short* __restrict__ hvW0t, const float* __restrict__ hvb0,
    const float* __restrict__ outW0, const float* __restrict__ outb0,
    const float* __restrict__ outW1, const float* __restrict__ outb1,
    float* __restrict__ dout)
{
  __shared__ __align__(16) unsigned short buf0[64 * kPitch];  // o, then m0 (hv0)
  __shared__ __align__(16) unsigned short buf1[64 * kPitch];  // mod, then S
  __shared__ __align__(16) unsigned short hbuf[16 * kPitch];  // h0, then h1 (per-pixel)
  __shared__ __align__(16) float scratch[64 * 3 * 4];         // out partials [row][k][wave]

  int tid = threadIdx.x;
  int px0 = blockIdx.x * 16;
  int w = tid >> 6, ln = tid & 63;
  int c = ln & 15, q = ln >> 4;

  // ---- stage o (64 rows x 128) and h0 (16 px x 256) ----
#pragma unroll
  for (int i = 0; i < 4; i++) {
    int idx = i * 256 + tid;              // 1024 x uint4 (8 fp16)
    int r = idx >> 4, c8 = (idx & 15) * 8;
    int b = r >> 4, px = r & 15;
    uint4 v = *(const uint4*)(o_hf + ((size_t)(b * kHW + px0 + px)) * 128 + c8);
    *(uint4*)&buf0[r * kPitch + c8] = v;
  }
#pragma unroll
  for (int i = 0; i < 2; i++) {
    int idx = i * 256 + tid;              // 512 x uint4
    int p = idx >> 5, c8 = (idx & 31) * 8;
    uint4 v = *(const uint4*)(h0_hf + ((size_t)(px0 + p)) * 256 + c8);
    *(uint4*)&hbuf[p * kPitch + c8] = v;
  }
  __syncthreads();

  f32x4 acc[16];
  const f32x4 zero4 = {0.f, 0.f, 0.f, 0.f};

  // ---- P1: mod = o @ tooW + toob -> buf1 ----
#pragma unroll
  for (int i = 0; i < 16; i++) acc[i] = zero4;
  gemm4<128>(buf0, tooWt + (size_t)w * 64 * 128, acc, c, q);
  {
    float bias[4];
#pragma unroll
    for (int nt = 0; nt < 4; nt++) bias[nt] = toob[w * 64 + nt * 16 + c];
#pragma unroll
    for (int mt = 0; mt < 4; mt++)
#pragma unroll
      for (int nt = 0; nt < 4; nt++)
#pragma unroll
        for (int rg = 0; rg < 4; rg++) {
          int row = mt * 16 + q * 4 + rg, col = w * 64 + nt * 16 + c;
          buf1[row * kPitch + col] = f2h(acc[mt * 4 + nt][rg] + bias[nt]);
        }
  }
  __syncthreads();   // barrier A: mod ready; all o reads done

  // ---- P2: m0 = relu(h0 + mod @ modW0 + b) -> buf0 ----
#pragma unroll
  for (int i = 0; i < 16; i++) acc[i] = zero4;
  gemm4<256>(buf1, modW0t + (size_t)w * 64 * 256, acc, c, q);
  {
    float bias[4], hr[4][4];
#pragma unroll
    for (int nt = 0; nt < 4; nt++) {
      int col = w * 64 + nt * 16 + c;
      bias[nt] = modb0[col];
#pragma unroll
      for (int rg = 0; rg < 4; rg++)
        hr[nt][rg] = h2f(hbuf[(q * 4 + rg) * kPitch + col]);
    }
#pragma unroll
    for (int mt = 0; mt < 4; mt++)
#pragma unroll
      for (int nt = 0; nt < 4; nt++)
#pragma unroll
        for (int rg = 0; rg < 4; rg++) {
          int row = mt * 16 + q * 4 + rg, col = w * 64 + nt * 16 + c;
          buf0[row * kPitch + col] =
              f2h(fmaxf(acc[mt * 4 + nt][rg] + bias[nt] + hr[nt][rg], 0.f));
        }
  }
  __syncthreads();   // barrier B: h0 consumed, m0 in buf0

  // ---- P3: stage h1; m1 = relu(h1 + mod @ modW1 + b); S = m0 + m1 -> buf1 ----
#pragma unroll
  for (int i = 0; i < 2; i++) {
    int idx = i * 256 + tid;
    int p = idx >> 5, c8 = (idx & 31) * 8;
    uint4 v = *(const uint4*)(h1_hf + ((size_t)(px0 + p)) * 256 + c8);
    *(uint4*)&hbuf[p * kPitch + c8] = v;
  }
#pragma unroll
  for (int i = 0; i < 16; i++) acc[i] = zero4;
  gemm4<256>(buf1, modW1t + (size_t)w * 64 * 256, acc, c, q);
  __syncthreads();   // barrier C: h1 staged AND all mod reads done
  {
    float bias[4], hr[4][4];
#pragma unroll
    for (int nt = 0; nt < 4; nt++) {
      int col = w * 64 + nt * 16 + c;
      bias[nt] = modb1[col];
#pragma unroll
      for (int rg = 0; rg < 4; rg++)
        hr[nt][rg] = h2f(hbuf[(q * 4 + rg) * kPitch + col]);
    }
#pragma unroll
    for (int mt = 0; mt < 4; mt++)
#pragma unroll
      for (int nt = 0; nt < 4; nt++)
#pragma unroll
        for (int rg = 0; rg < 4; rg++) {
          int row = mt * 16 + q * 4 + rg, col = w * 64 + nt * 16 + c;
          float m0v = h2f(buf0[row * kPitch + col]);
          float v = m0v + fmaxf(acc[mt * 4 + nt][rg] + bias[nt] + hr[nt][rg], 0.f);
          buf1[row * kPitch + col] = f2h(v);
        }
  }
  __syncthreads();   // barrier D: S ready

  // ---- P4: hv1 = relu(S @ hvW0 + b); fused out epilogue ----
#pragma unroll
  for (int i = 0; i < 16; i++) acc[i] = zero4;
  gemm4<256>(buf1, hvW0t + (size_t)w * 64 * 256, acc, c, q);
  {
    float bias[4], w0v[4][3], w1v[4][3];
#pragma unroll
    for (int nt = 0; nt < 4; nt++) {
      int col = w * 64 + nt * 16 + c;
      bias[nt] = hvb0[col];
#pragma unroll
      for (int k = 0; k < 3; k++) {
        w0v[nt][k] = outW0[col * 3 + k];
        w1v[nt][k] = outW1[col * 3 + k];
      }
    }
#pragma unroll
    for (int mt = 0; mt < 4; mt++) {
      float pk[4][3];
#pragma unroll
      for (int rg = 0; rg < 4; rg++)
#pragma unroll
        for (int k = 0; k < 3; k++) pk[rg][k] = 0.f;
#pragma unroll
      for (int nt = 0; nt < 4; nt++) {
        int col = w * 64 + nt * 16 + c;
#pragma unroll
        for (int rg = 0; rg < 4; rg++) {
          int row = mt * 16 + q * 4 + rg;
          float hv1 = fmaxf(acc[mt * 4 + nt][rg] + bias[nt], 0.f);
          float m0v = h2f(buf0[row * kPitch + col]);
#pragma unroll
          for (int k = 0; k < 3; k++)
            pk[rg][k] += m0v * w0v[nt][k] + hv1 * w1v[nt][k];
        }
      }
#pragma unroll
      for (int s = 1; s < 16; s <<= 1)
#pragma unroll
        for (int rg = 0; rg < 4; rg++)
#pragma unroll
          for (int k = 0; k < 3; k++)
            pk[rg][k] += __shfl_xor(pk[rg][k], s, 64);
      if (c == 0) {
#pragma unroll
        for (int rg = 0; rg < 4; rg++) {
          int row = mt * 16 + q * 4 + rg;
#pragma unroll
          for (int k = 0; k < 3; k++)
            scratch[row * 12 + k * 4 + w] = pk[rg][k];
        }
      }
    }
  }
  __syncthreads();

  if (tid < 192) {
    int row = tid / 3, k = tid % 3;
    int b = row >> 4, px = px0 + (row & 15);
    float s = outb0[k] + outb1[k];
#pragma unroll
    for (int ww = 0; ww < 4; ww++) s += scratch[row * 12 + k * 4 + ww];
    dout[((size_t)b * kHW + px) * 3 + k] = s;
  }
}

// ---------------- launch ----------------
extern "C" void kernel_launch(void* const* d_in, const int* in_sizes, int n_in,
                              void* d_out, int out_size, void* d_ws, size_t ws_size,
                              hipStream_t stream) {
  const float* coords = (const float*)d_in[0];
  const float* tokens = (const float*)d_in[1];
  const float* Bq     = (const float*)d_in[2];
  const float* Bl0    = (const float*)d_in[3];
  const float* Bl1    = (const float*)d_in[4];
  const float* qW     = (const float*)d_in[5];
  const float* qb     = (const float*)d_in[6];
  const float* toqW   = (const float*)d_in[7];
  const float* tokvW  = (const float*)d_in[8];
  const float* tooW   = (const float*)d_in[9];
  const float* toob   = (const float*)d_in[10];
  const float* bwW0   = (const float*)d_in[11];
  const float* bwb0   = (const float*)d_in[12];
  const float* bwW1   = (const float*)d_in[13];
  const float* bwb1   = (const float*)d_in[14];
  const float* modW0  = (const float*)d_in[15];
  const float* modb0  = (const float*)d_in[16];
  const float* modW1  = (const float*)d_in[17];
  const float* modb1  = (const float*)d_in[18];
  const float* hvW0   = (const float*)d_in[19];
  const float* hvb0   = (const float*)d_in[20];
  const float* outW0  = (const float*)d_in[21];
  const float* outb0  = (const float*)d_in[22];
  const float* outW1  = (const float*)d_in[23];
  const float* outb1  = (const float*)d_in[24];

  char* ws = (char*)d_ws;
  unsigned short* qc_ws  = (unsigned short*)(ws + 65536);     //    4 MB
  unsigned short* h0_hf  = (unsigned short*)(ws + 4259840);   //    8 MB
  unsigned short* h1_hf  = (unsigned short*)(ws + 12648448);  //    8 MB
  unsigned short* o_hf   = (unsigned short*)(ws + 21037056);  //   16 MB
  unsigned short* kn_ws  = (unsigned short*)(ws + 37814272);  //  256 KB
  unsigned short* vt_ws  = (unsigned short*)(ws + 38076416);  //  256 KB
  unsigned short* tooWt  = (unsigned short*)(ws + 38338560);  //   64 KB
  unsigned short* modW0t = (unsigned short*)(ws + 38404096);  //  128 KB
  unsigned short* modW1t = (unsigned short*)(ws + 38535168);  //  128 KB
  unsigned short* hvW0t  = (unsigned short*)(ws + 38666240);  //  128 KB
  unsigned short* qWt    = (unsigned short*)(ws + 38797312);  //   32 KB
  unsigned short* bw0t   = (unsigned short*)(ws + 38830080);  //   32 KB
  unsigned short* bw1t   = (unsigned short*)(ws + 38862848);  //   32 KB
  unsigned short* toqWt  = (unsigned short*)(ws + 38895616);  //   64 KB

  wprep_kernel<<<dim3(8), 256, 0, stream>>>(
      tooW, modW0, modW1, hvW0, qW, bwW0, bwW1, toqW,
      tooWt, modW0t, modW1t, hvW0t, qWt, bw0t, bw1t, toqWt);
  feat_kernel<<<dim3(kHW / 32), 256, 0, stream>>>(
      coords, Bq, Bl0, Bl1, qb, bwb0, bwb1,
      qWt, bw0t, bw1t, toqWt,
      qc_ws, h0_hf, h1_hf);
  kv_kernel<<<dim3(kM, kB), 256, 0, stream>>>(tokens, tokvW, kn_ws, vt_ws);
  attn_kernel<<<dim3(kHW / 64, kB), 256, 0, stream>>>(kn_ws, vt_ws, qc_ws, coords, o_hf);
  mlp_kernel<<<dim3(kHW / 16), 256, 0, stream>>>(
      o_hf, h0_hf, h1_hf, tooWt, toob, modW0t, modb0, modW1t, modb1,
      hvW0t, hvb0, outW0, outb0, outW1, outb1, (float*)d_out);
}